// Round 1
// baseline (294.440 us; speedup 1.0000x reference)
//
#include <hip/hip_runtime.h>
#include <math.h>

// Problem dims (fixed by setup_inputs)
namespace {
constexpr int Bn = 4, Cn = 128, Tn = 32, Hn = 24, Wn = 24, Mn = 3;
constexpr int HWn = Hn * Wn;      // 576
constexpr int TTile = 8;          // time tile per block in conv kernel
constexpr int PL = TTile + 2;     // input planes per tile (causal halo 2)
constexpr int RS = 28;            // LDS row stride (26 cols + pad, 16B-aligned rows)
constexpr int PS = 26 * RS;       // plane stride in LDS floats
}

// ---------------- Kernel A: spatial mean pool q -> qg[B*C*T] ----------------
__global__ __launch_bounds__(64) void pool_kernel(const float* __restrict__ q,
                                                  float* __restrict__ qg) {
    int bct = blockIdx.x;
    const float* p = q + (size_t)bct * HWn;
    int lane = threadIdx.x;
    float s = 0.f;
#pragma unroll
    for (int j = 0; j < 9; ++j) s += p[lane + j * 64];   // 576 = 9*64, coalesced
#pragma unroll
    for (int off = 32; off > 0; off >>= 1) s += __shfl_down(s, off);
    if (lane == 0) qg[bct] = s * (1.0f / 576.0f);
}

// ---------------- Kernel B: alpha[B*M*T] from qg ----------------
__global__ __launch_bounds__(512) void alpha_kernel(const float* __restrict__ qg,
                                                    const float* __restrict__ pre_w,
                                                    const float* __restrict__ pre_b,
                                                    const float* __restrict__ mix_w,
                                                    const float* __restrict__ mix_b,
                                                    float* __restrict__ alpha) {
    __shared__ float qg_s[Cn * Tn];          // [c][t]
    __shared__ float h_s[Cn * (Tn + 2)];     // [c][t+2], cols 0..1 are causal zero pad
    __shared__ float l_s[Mn * Tn];
    int b = blockIdx.x;
    int tid = threadIdx.x;
    for (int i = tid; i < Cn * Tn; i += 512) qg_s[i] = qg[b * Cn * Tn + i];
    __syncthreads();
    // h[o,t] = gelu(pre_w[o,:]·qg[:,t] + pre_b[o]); thread = (o, quarter-of-t)
    {
        int o = tid >> 2;
        int t0 = (tid & 3) * 8;
        float bias = pre_b[o];
        float acc[8];
#pragma unroll
        for (int j = 0; j < 8; ++j) acc[j] = bias;
        const float* wrow = pre_w + o * Cn;
#pragma unroll 4
        for (int c = 0; c < Cn; ++c) {
            float wv = wrow[c];
#pragma unroll
            for (int j = 0; j < 8; ++j) acc[j] += wv * qg_s[c * Tn + t0 + j];
        }
        if ((tid & 3) == 0) { h_s[o * (Tn + 2) + 0] = 0.f; h_s[o * (Tn + 2) + 1] = 0.f; }
#pragma unroll
        for (int j = 0; j < 8; ++j) {
            float x = acc[j];
            // exact GELU: x * 0.5 * (1 + erf(x/sqrt(2)))
            h_s[o * (Tn + 2) + 2 + t0 + j] = 0.5f * x * (1.0f + erff(x * 0.70710678118654752f));
        }
    }
    __syncthreads();
    // causal conv1d C->M over time (k=3, left pad 2)
    if (tid < Mn * Tn) {
        int m = tid / Tn, t = tid % Tn;
        float acc = mix_b[m];
#pragma unroll 4
        for (int c = 0; c < Cn; ++c) {
            const float* mw = mix_w + (m * Cn + c) * 3;
            const float* hp = h_s + c * (Tn + 2) + t;  // h[t-2+j] lives at col t+j
            acc += mw[0] * hp[0] + mw[1] * hp[1] + mw[2] * hp[2];
        }
        l_s[m * Tn + t] = acc;
    }
    __syncthreads();
    if (tid < Tn) {
        int t = tid;
        float l0 = l_s[t], l1 = l_s[Tn + t], l2 = l_s[2 * Tn + t];
        float mx = fmaxf(l0, fmaxf(l1, l2));
        float e0 = expf(l0 - mx), e1 = expf(l1 - mx), e2 = expf(l2 - mx);
        float inv = 1.0f / (e0 + e1 + e2);
        alpha[(b * Mn + 0) * Tn + t] = e0 * inv;
        alpha[(b * Mn + 1) * Tn + t] = e1 * inv;
        alpha[(b * Mn + 2) * Tn + t] = e2 * inv;
    }
}

// ---------------- Kernel C: fused dwconv3d(k,v) with pre-mixed weights ----------------
// grid: B*C*(T/TTile) blocks, 384 threads. Per block: one (b,c), 8 output time steps.
__global__ __launch_bounds__(384) void conv_kernel(const float* __restrict__ kin,
                                                   const float* __restrict__ vin,
                                                   const float* __restrict__ Wk,
                                                   const float* __restrict__ Wv,
                                                   const float* __restrict__ alpha,
                                                   float* __restrict__ out) {
    __shared__ float sk[PL * PS];           // 10 planes, 26x26 halo'd, stride 28
    __shared__ float sv[PL * PS];
    __shared__ float sw[TTile * 2 * 27];    // [t_local][branch][27] mixed weights

    int bid = blockIdx.x;
    int tt = bid & 3;
    int c  = (bid >> 2) & 127;
    int b  = bid >> 9;
    int t0 = tt * TTile;
    int tid = threadIdx.x;
    const size_t plane_base = (size_t)(b * Cn + c) * Tn;   // plane index into [B,C,T] planes

    // Stage k/v planes into LDS with zero halo (spatial same-pad, causal time pad)
    for (int idx = tid; idx < PL * 26 * 26; idx += 384) {
        int p = idx / 676;
        int cell = idx - p * 676;
        int r = cell / 26;
        int cl = cell - r * 26;
        int tp = t0 - 2 + p;
        int h = r - 1, w = cl - 1;
        float vk = 0.f, vv = 0.f;
        if (tp >= 0 && (unsigned)h < (unsigned)Hn && (unsigned)w < (unsigned)Wn) {
            size_t off = (plane_base + tp) * HWn + h * Wn + w;
            vk = kin[off];
            vv = vin[off];
        }
        sk[p * PS + r * RS + cl] = vk;
        sv[p * PS + r * RS + cl] = vv;
    }
    // Mix weights: W_eff[t,branch] = sum_m alpha[b,m,t0+t] * W{k,v}[m,c,:]
    for (int i = tid; i < TTile * 2 * 27; i += 384) {
        int tl = i / 54;
        int r = i - tl * 54;
        int br = r / 27;
        int widx = r - br * 27;
        const float* Wb = br ? Wv : Wk;
        float a0 = alpha[(b * Mn + 0) * Tn + t0 + tl];
        float a1 = alpha[(b * Mn + 1) * Tn + t0 + tl];
        float a2 = alpha[(b * Mn + 2) * Tn + t0 + tl];
        sw[i] = a0 * Wb[(0 * Cn + c) * 27 + widx]
              + a1 * Wb[(1 * Cn + c) * 27 + widx]
              + a2 * Wb[(2 * Cn + c) * 27 + widx];
    }
    __syncthreads();

    // Compute: thread = (t_local, h, half-row of 12 outputs)
    int tl = tid / 48;
    int rem = tid - tl * 48;
    int h = rem >> 1;
    int w0 = (rem & 1) * 12;
    const float* wk = sw + tl * 54;
    const float* wv = wk + 27;
    float acck[12], accv[12];
#pragma unroll
    for (int j = 0; j < 12; ++j) { acck[j] = 0.f; accv[j] = 0.f; }
#pragma unroll
    for (int dt = 0; dt < 3; ++dt) {
#pragma unroll
        for (int dh = 0; dh < 3; ++dh) {
            const float* rk = sk + (tl + dt) * PS + (h + dh) * RS + w0;  // 16B-aligned
            const float* rv = sv + (tl + dt) * PS + (h + dh) * RS + w0;
            float bk[14], bv[14];
#pragma unroll
            for (int j = 0; j < 14; ++j) { bk[j] = rk[j]; bv[j] = rv[j]; }
#pragma unroll
            for (int dw = 0; dw < 3; ++dw) {
                float wkc = wk[dt * 9 + dh * 3 + dw];
                float wvc = wv[dt * 9 + dh * 3 + dw];
#pragma unroll
                for (int j = 0; j < 12; ++j) {
                    acck[j] += bk[j + dw] * wkc;
                    accv[j] += bv[j + dw] * wvc;
                }
            }
        }
    }
    size_t obase = (plane_base + t0 + tl) * HWn + h * Wn + w0;   // float4-aligned
    float* ok = out + obase;
    float* ov = out + (size_t)Bn * Cn * Tn * HWn + obase;
#pragma unroll
    for (int j = 0; j < 3; ++j) {
        ((float4*)ok)[j] = make_float4(acck[4 * j], acck[4 * j + 1], acck[4 * j + 2], acck[4 * j + 3]);
        ((float4*)ov)[j] = make_float4(accv[4 * j], accv[4 * j + 1], accv[4 * j + 2], accv[4 * j + 3]);
    }
}

extern "C" void kernel_launch(void* const* d_in, const int* in_sizes, int n_in,
                              void* d_out, int out_size, void* d_ws, size_t ws_size,
                              hipStream_t stream) {
    const float* q     = (const float*)d_in[0];
    const float* k     = (const float*)d_in[1];
    const float* v     = (const float*)d_in[2];
    const float* Wk    = (const float*)d_in[3];
    const float* Wv    = (const float*)d_in[4];
    const float* pre_w = (const float*)d_in[5];
    const float* pre_b = (const float*)d_in[6];
    const float* mix_w = (const float*)d_in[7];
    const float* mix_b = (const float*)d_in[8];
    float* out = (float*)d_out;

    float* qg    = (float*)d_ws;            // B*C*T = 16384 floats
    float* alpha = qg + Bn * Cn * Tn;       // B*M*T = 384 floats

    hipLaunchKernelGGL(pool_kernel, dim3(Bn * Cn * Tn), dim3(64), 0, stream, q, qg);
    hipLaunchKernelGGL(alpha_kernel, dim3(Bn), dim3(512), 0, stream,
                       qg, pre_w, pre_b, mix_w, mix_b, alpha);
    hipLaunchKernelGGL(conv_kernel, dim3(Bn * Cn * (Tn / TTile)), dim3(384), 0, stream,
                       k, v, Wk, Wv, alpha, out);
}

// Round 2
// 214.997 us; speedup vs baseline: 1.3695x; 1.3695x over previous
//
#include <hip/hip_runtime.h>
#include <math.h>

// Problem dims (fixed by setup_inputs)
namespace {
constexpr int Bn = 4, Cn = 128, Tn = 32, Hn = 24, Wn = 24, Mn = 3;
constexpr int HWn = Hn * Wn;      // 576
constexpr int TTile = 8;          // time tile per conv block
constexpr int PL = TTile + 2;     // input planes per tile (causal halo 2)
constexpr int RS = 28;            // LDS row stride (1 left pad + 24 data + 3 pad)
constexpr int PS = 26 * RS;       // plane stride in LDS floats (728)
}

// ---------------- Kernel A: spatial mean pool q -> qg[B*C*T] ----------------
// 4 planes per 256-thread block (1 wave per plane), float4 loads.
__global__ __launch_bounds__(256) void pool_kernel(const float* __restrict__ q,
                                                   float* __restrict__ qg) {
    int wave = threadIdx.x >> 6;
    int lane = threadIdx.x & 63;
    int plane = blockIdx.x * 4 + wave;
    const float4* p = (const float4*)(q + (size_t)plane * HWn);  // 144 float4
    float4 a = p[lane];
    float4 b = p[lane + 64];
    float s = (a.x + a.y) + (a.z + a.w) + (b.x + b.y) + (b.z + b.w);
    if (lane < 16) {
        float4 c = p[128 + lane];
        s += (c.x + c.y) + (c.z + c.w);
    }
#pragma unroll
    for (int off = 32; off > 0; off >>= 1) s += __shfl_down(s, off);
    if (lane == 0) qg[plane] = s * (1.0f / 576.0f);
}

// ---------------- Kernel B: alpha[B*M*T] from qg ----------------
__global__ __launch_bounds__(512) void alpha_kernel(const float* __restrict__ qg,
                                                    const float* __restrict__ pre_w,
                                                    const float* __restrict__ pre_b,
                                                    const float* __restrict__ mix_w,
                                                    const float* __restrict__ mix_b,
                                                    float* __restrict__ alpha) {
    __shared__ float qg_s[Cn * Tn];          // [c][t]
    __shared__ float h_s[Cn * (Tn + 2)];     // [c][t+2], cols 0..1 causal zero pad
    __shared__ float mw_s[Mn * Cn * 3];
    __shared__ float l_s[Mn * Tn];
    int b = blockIdx.x;
    int tid = threadIdx.x;
    for (int i = tid; i < Cn * Tn; i += 512) qg_s[i] = qg[b * Cn * Tn + i];
    for (int i = tid; i < Mn * Cn * 3; i += 512) mw_s[i] = mix_w[i];
    __syncthreads();
    // h[o,t] = gelu(pre_w[o,:]·qg[:,t] + pre_b[o]); thread = (o, quarter-of-t)
    {
        int o = tid >> 2;
        int t0 = (tid & 3) * 8;
        float bias = pre_b[o];
        float acc[8];
#pragma unroll
        for (int j = 0; j < 8; ++j) acc[j] = 0.f;
        const float* wrow = pre_w + o * Cn;
#pragma unroll 2
        for (int cb = 0; cb < Cn; cb += 8) {
            float wv[8];
#pragma unroll
            for (int j = 0; j < 8; ++j) wv[j] = wrow[cb + j];   // 8 loads in flight
#pragma unroll
            for (int j = 0; j < 8; ++j)
#pragma unroll
                for (int i = 0; i < 8; ++i)
                    acc[i] += wv[j] * qg_s[(cb + j) * Tn + t0 + i];
        }
        if ((tid & 3) == 0) { h_s[o * (Tn + 2) + 0] = 0.f; h_s[o * (Tn + 2) + 1] = 0.f; }
#pragma unroll
        for (int j = 0; j < 8; ++j) {
            float x = acc[j] + bias;
            h_s[o * (Tn + 2) + 2 + t0 + j] = 0.5f * x * (1.0f + erff(x * 0.70710678118654752f));
        }
    }
    __syncthreads();
    // causal conv1d C->M over time (k=3, left pad 2), from LDS
    if (tid < Mn * Tn) {
        int m = tid / Tn, t = tid % Tn;
        float acc = mix_b[m];
#pragma unroll 8
        for (int c = 0; c < Cn; ++c) {
            const float* mw = mw_s + (m * Cn + c) * 3;
            const float* hp = h_s + c * (Tn + 2) + t;  // h[t-2+j] lives at col t+j
            acc += mw[0] * hp[0] + mw[1] * hp[1] + mw[2] * hp[2];
        }
        l_s[m * Tn + t] = acc;
    }
    __syncthreads();
    if (tid < Tn) {
        int t = tid;
        float l0 = l_s[t], l1 = l_s[Tn + t], l2 = l_s[2 * Tn + t];
        float mx = fmaxf(l0, fmaxf(l1, l2));
        float e0 = expf(l0 - mx), e1 = expf(l1 - mx), e2 = expf(l2 - mx);
        float inv = 1.0f / (e0 + e1 + e2);
        alpha[(b * Mn + 0) * Tn + t] = e0 * inv;
        alpha[(b * Mn + 1) * Tn + t] = e1 * inv;
        alpha[(b * Mn + 2) * Tn + t] = e2 * inv;
    }
}

// ---------------- Kernel C: dwconv3d with pre-mixed weights ----------------
// grid: 2*B*C*(T/TTile) blocks of 384; branch (k vs v) in top bid bit.
// LDS ~30 KiB -> 5 blocks/CU (30/32 waves).
__global__ __launch_bounds__(384) void conv_kernel(const float* __restrict__ kin,
                                                   const float* __restrict__ vin,
                                                   const float* __restrict__ Wk,
                                                   const float* __restrict__ Wv,
                                                   const float* __restrict__ alpha,
                                                   float* __restrict__ out) {
    __shared__ float s[PL * PS];          // 10 planes, 26x28 (1 left pad, 24 data)
    __shared__ float sw[TTile * 27];      // per-t mixed weights

    int bid = blockIdx.x;
    int tt = bid & 3;
    int c  = (bid >> 2) & 127;
    int b  = (bid >> 9) & 3;
    int br = bid >> 11;                   // 0 = k branch, 1 = v branch
    int t0 = tt * TTile;
    int tid = threadIdx.x;
    const size_t plane_base = (size_t)(b * Cn + c) * Tn;
    const float* __restrict__ src = br ? vin : kin;
    const float* __restrict__ Wb  = br ? Wv : Wk;

    // 1) zero-fill LDS (halo + causal pad), vectorized
    float4 z4 = make_float4(0.f, 0.f, 0.f, 0.f);
    for (int i = tid; i < PL * PS / 4; i += 384) ((float4*)s)[i] = z4;
    __syncthreads();

    // 2) interior fill: coalesced float4 global loads, plane-level tp check only
    for (int idx = tid; idx < PL * 144; idx += 384) {       // 144 float4 per plane
        int p = idx / 144;
        int cell = idx - p * 144;
        int r = cell / 6;
        int c4 = cell - r * 6;
        int tp = t0 - 2 + p;
        if (tp >= 0) {
            float4 val = *(const float4*)(src + (plane_base + tp) * HWn + r * 24 + c4 * 4);
            float* dst = s + p * PS + (r + 1) * RS + 1 + c4 * 4;
            dst[0] = val.x; dst[1] = val.y; dst[2] = val.z; dst[3] = val.w;
        }
    }
    // 3) mix weights: W_eff[t] = sum_m alpha[b,m,t0+t] * Wb[m,c,:]
    if (tid < TTile * 27) {
        int tl = tid / 27;
        int widx = tid - tl * 27;
        float a0 = alpha[(b * Mn + 0) * Tn + t0 + tl];
        float a1 = alpha[(b * Mn + 1) * Tn + t0 + tl];
        float a2 = alpha[(b * Mn + 2) * Tn + t0 + tl];
        sw[tid] = a0 * Wb[(0 * Cn + c) * 27 + widx]
                + a1 * Wb[(1 * Cn + c) * 27 + widx]
                + a2 * Wb[(2 * Cn + c) * 27 + widx];
    }
    __syncthreads();

    // 4) compute: thread = (t_local, h, half-row of 12 outputs)
    int tl = tid / 48;
    int rem = tid - tl * 48;
    int h = rem >> 1;
    int w0 = (rem & 1) * 12;
    const float* wp = sw + tl * 27;
    float acc[12];
#pragma unroll
    for (int j = 0; j < 12; ++j) acc[j] = 0.f;
#pragma unroll
    for (int dt = 0; dt < 3; ++dt) {
#pragma unroll
        for (int dh = 0; dh < 3; ++dh) {
            const float* rp = s + (tl + dt) * PS + (h + dh) * RS + w0;  // 16B-aligned
            float bf[14];
#pragma unroll
            for (int j = 0; j < 14; ++j) bf[j] = rp[j];
#pragma unroll
            for (int dw = 0; dw < 3; ++dw) {
                float wc = wp[dt * 9 + dh * 3 + dw];
#pragma unroll
                for (int j = 0; j < 12; ++j) acc[j] += bf[j + dw] * wc;
            }
        }
    }
    size_t obase = (plane_base + t0 + tl) * HWn + h * Wn + w0;   // float4-aligned
    float* op = out + (br ? (size_t)Bn * Cn * Tn * HWn : 0) + obase;
#pragma unroll
    for (int j = 0; j < 3; ++j)
        ((float4*)op)[j] = make_float4(acc[4*j], acc[4*j+1], acc[4*j+2], acc[4*j+3]);
}

extern "C" void kernel_launch(void* const* d_in, const int* in_sizes, int n_in,
                              void* d_out, int out_size, void* d_ws, size_t ws_size,
                              hipStream_t stream) {
    const float* q     = (const float*)d_in[0];
    const float* k     = (const float*)d_in[1];
    const float* v     = (const float*)d_in[2];
    const float* Wk    = (const float*)d_in[3];
    const float* Wv    = (const float*)d_in[4];
    const float* pre_w = (const float*)d_in[5];
    const float* pre_b = (const float*)d_in[6];
    const float* mix_w = (const float*)d_in[7];
    const float* mix_b = (const float*)d_in[8];
    float* out = (float*)d_out;

    float* qg    = (float*)d_ws;            // B*C*T = 16384 floats
    float* alpha = qg + Bn * Cn * Tn;       // B*M*T = 384 floats

    hipLaunchKernelGGL(pool_kernel, dim3(Bn * Cn * Tn / 4), dim3(256), 0, stream, q, qg);
    hipLaunchKernelGGL(alpha_kernel, dim3(Bn), dim3(512), 0, stream,
                       qg, pre_w, pre_b, mix_w, mix_b, alpha);
    hipLaunchKernelGGL(conv_kernel, dim3(2 * Bn * Cn * (Tn / TTile)), dim3(384), 0, stream,
                       k, v, Wk, Wv, alpha, out);
}